// Round 7
// baseline (3462.032 us; speedup 1.0000x reference)
//
#include <hip/hip_runtime.h>
#include <hip/hip_bf16.h>
#include <hip/hip_cooperative_groups.h>

namespace cg = cooperative_groups;

#define N_USER 50000
#define N_ITEM 30000
#define NTOT   80000
#define EMB    64
#define FAC    4
#define EDGES  1000000
#define LOG4   1.3862943611198906f
#define NBUCK  512   // h-buckets for CSR build
#define BBLK   512   // blocks in count/scatter phases
#define BCH    1954  // ceil(EDGES/BBLK)
#define GRID   2048  // cooperative grid (8 blocks/CU @ 256 CU)

// ws layout (float idx), ~90 MB:
//   P     +0          4,000,000  (softmax probs; overlapped early by bt/cnt/gbase —
//                                 all dead before P first written in upd0)
//   dvA   +4,000,000    320,000  (dval ping; seeded 0.25*deg by bfin)
//   dvB   +4,320,000    320,000  (dval pong)
//   rhn   +4,640,000    320,000
//   bufW  +4,960,000  2,560,000  (bf16: input ego)
//   bufX  +7,520,000  2,560,000  (bf16: f0 / f2)
//   bufY  +10,080,000 2,560,000  (bf16: f1 = layer-1 input)
//   bufZ0 +12,640,000 2,560,000  (bf16: layer-0 tanh-norm)
//   bufZ1 +15,200,000 2,560,000  (bf16: layer-1 tanh-norm)
//   flag  +20,320,000 16 | boff +20,320,016 513 | btot +20,321,000 512
//   off   +20,400,016 80,001
//   tlist +20,480,017 1,000,000 | hlist +21,480,017 1,000,000

__device__ inline float bf2f(unsigned short u) {
    return __uint_as_float(((unsigned int)u) << 16);
}
__device__ inline unsigned short f2bf(float f) {
    unsigned int x = __float_as_uint(f);
    x += 0x7FFFu + ((x >> 16) & 1u);       // round-to-nearest-even
    return (unsigned short)(x >> 16);
}
__device__ inline float dot2(unsigned int a, unsigned int b) {
    float a0 = __uint_as_float(a << 16), a1 = __uint_as_float(a & 0xFFFF0000u);
    float b0 = __uint_as_float(b << 16), b1 = __uint_as_float(b & 0xFFFF0000u);
    return a0 * b0 + a1 * b1;
}
__device__ inline int bucket_of(int h) { return (int)(((unsigned)h * NBUCK) / (unsigned)NTOT); }
__device__ inline int bucket_lo(int k) { return (k * NTOT + NBUCK - 1) / NBUCK; }

// ===================== shared phase bodies =====================

__device__ __forceinline__ void d_init_body(
    int wid, int lane, const void* ue, const void* ie, int isf32,
    unsigned short* egoh, unsigned short* tnh0)
{
    if (wid >= NTOT) return;
    int i = wid * 64 + lane;
    float v;
    if (i < N_USER * EMB) {
        v = isf32 ? ((const float*)ue)[i]
                  : __bfloat162float(((const __hip_bfloat16*)ue)[i]);
    } else {
        int j = i - N_USER * EMB;
        v = isf32 ? ((const float*)ie)[j]
                  : __bfloat162float(((const __hip_bfloat16*)ie)[j]);
    }
    egoh[i] = f2bf(v);
    float ss = v * v;
    ss += __shfl_xor(ss, 1); ss += __shfl_xor(ss, 2);
    ss += __shfl_xor(ss, 4); ss += __shfl_xor(ss, 8);
    float rr = 1.0f / fmaxf(sqrtf(ss), 1e-12f);
    tnh0[i] = f2bf(tanhf(v * rr));
}

__device__ __forceinline__ void d_bcnt_body(
    int b, int tid, int* hist, const int* hl, int* cnt)
{
    for (int i = tid; i < NBUCK; i += 256) hist[i] = 0;
    __syncthreads();
    int base = b * BCH, end = base + BCH; if (end > EDGES) end = EDGES;
    for (int e = base + tid; e < end; e += 256)
        atomicAdd(&hist[bucket_of(hl[e])], 1);
    __syncthreads();
    for (int i = tid; i < NBUCK; i += 256) cnt[b * NBUCK + i] = hist[i];
    __syncthreads();
}

__device__ __forceinline__ void d_bscat_body(
    int b, int tid, int* lg, const int* hl, const int* tl,
    const int* gbase, int* bt)
{
    for (int i = tid; i < NBUCK; i += 256) lg[i] = gbase[b * NBUCK + i];
    __syncthreads();
    int base = b * BCH, end = base + BCH; if (end > EDGES) end = EDGES;
    for (int e = base + tid; e < end; e += 256) {
        int h = hl[e];
        int k = bucket_of(h);
        int pos = atomicAdd(&lg[k], 1);
        bt[pos] = ((h - bucket_lo(k)) << 17) | tl[e];
    }
    __syncthreads();
}

__device__ __forceinline__ void d_bfin_body(
    int k, int tid, int* ldeg, int* lcur, int* sbuf,
    const int* bt, const int* boff, int* off, float* dvacc,
    int* tlist, int* hlist)
{
    int lo = bucket_lo(k), hi = bucket_lo(k + 1);
    int nn = hi - lo;                 // 156 or 157
    for (int i = tid; i < nn; i += 256) ldeg[i] = 0;
    __syncthreads();
    int start = boff[k], end = boff[k + 1];
    for (int j = start + tid; j < end; j += 256)
        atomicAdd(&ldeg[bt[j] >> 17], 1);
    __syncthreads();
    int v = (tid < nn) ? ldeg[tid] : 0;
    sbuf[tid] = v;
    __syncthreads();
    for (int s = 1; s < 256; s <<= 1) {
        int t = (tid >= s) ? sbuf[tid - s] : 0;
        __syncthreads();
        sbuf[tid] += t;
        __syncthreads();
    }
    if (tid < nn) {
        int o = start + sbuf[tid] - v;
        off[lo + tid] = o;
        lcur[tid] = o;
        float d = 0.25f * (float)v;
        ((float4*)dvacc)[lo + tid] = make_float4(d, d, d, d);
    }
    if (k == 0 && tid == 0) off[NTOT] = EDGES;
    __syncthreads();
    for (int j = start + tid; j < end; j += 256) {
        int val = bt[j];
        int hrel = val >> 17;
        int t = val & 0x1FFFF;
        int pos = atomicAdd(&lcur[hrel], 1);
        tlist[pos] = t;
        hlist[pos] = lo + hrel;
    }
    __syncthreads();
}

// message passing body (round-6 proven inner loop, flag passed as int)
__device__ __forceinline__ void d_mp_body(
    int wid, int lane,
    const unsigned short* ego, const float* P,
    const float* dva, float* zb,
    const int* off, const int* tlist,
    unsigned short* fach, float* rhn, unsigned short* tnhOut,
    const unsigned short* f1b, const void* ue, const void* ie,
    int isf32, float* outF,
    int useP, int writeRhn, int writeTnh, int doFinal)
{
    if (wid >= NTOT) return;
    int c = lane & 15;   // column group: cols 4c..4c+3
    int q = lane >> 4;   // edge slot within group-of-4
    int f = c >> 2;      // factor of these columns
    if (zb != nullptr && lane < 4) zb[wid * 4 + lane] = 0.f;   // prezero next dval
    int beg = off[wid], end = off[wid + 1];
    float dvh = rsqrtf(fmaxf(dva[wid * 4 + f], 1e-8f));
    const uint2* eg2 = (const uint2*)ego;   // one row = 16 uint2 (128 B)

    float a0 = 0.f, a1 = 0.f, a2 = 0.f, a3 = 0.f;
    int nfull = (end - beg) >> 2;
    int j = beg + q;
    if (useP) {
#pragma unroll 2
        for (int g = 0; g < nfull; ++g, j += 4) {
            int t = tlist[j];
            float w = P[j * 4 + f];
            float dvt = rsqrtf(fmaxf(dva[t * 4 + f], 1e-8f));
            uint2 u = eg2[(size_t)t * 16 + c];
            w *= dvt;
            a0 += w * __uint_as_float(u.x << 16);
            a1 += w * __uint_as_float(u.x & 0xFFFF0000u);
            a2 += w * __uint_as_float(u.y << 16);
            a3 += w * __uint_as_float(u.y & 0xFFFF0000u);
        }
        if (j < end) {   // tail: 1-3 edges, exec-masked
            int t = tlist[j];
            float w = P[j * 4 + f];
            float dvt = rsqrtf(fmaxf(dva[t * 4 + f], 1e-8f));
            uint2 u = eg2[(size_t)t * 16 + c];
            w *= dvt;
            a0 += w * __uint_as_float(u.x << 16);
            a1 += w * __uint_as_float(u.x & 0xFFFF0000u);
            a2 += w * __uint_as_float(u.y << 16);
            a3 += w * __uint_as_float(u.y & 0xFFFF0000u);
        }
    } else {
#pragma unroll 2
        for (int g = 0; g < nfull; ++g, j += 4) {
            int t = tlist[j];
            float dvt = rsqrtf(fmaxf(dva[t * 4 + f], 1e-8f));
            uint2 u = eg2[(size_t)t * 16 + c];
            float w = 0.25f * dvt;
            a0 += w * __uint_as_float(u.x << 16);
            a1 += w * __uint_as_float(u.x & 0xFFFF0000u);
            a2 += w * __uint_as_float(u.y << 16);
            a3 += w * __uint_as_float(u.y & 0xFFFF0000u);
        }
        if (j < end) {
            int t = tlist[j];
            float dvt = rsqrtf(fmaxf(dva[t * 4 + f], 1e-8f));
            uint2 u = eg2[(size_t)t * 16 + c];
            float w = 0.25f * dvt;
            a0 += w * __uint_as_float(u.x << 16);
            a1 += w * __uint_as_float(u.x & 0xFFFF0000u);
            a2 += w * __uint_as_float(u.y << 16);
            a3 += w * __uint_as_float(u.y & 0xFFFF0000u);
        }
    }

    // combine the 4 edge slots (lane bits 4,5)
    a0 += __shfl_xor(a0, 16); a1 += __shfl_xor(a1, 16);
    a2 += __shfl_xor(a2, 16); a3 += __shfl_xor(a3, 16);
    a0 += __shfl_xor(a0, 32); a1 += __shfl_xor(a1, 32);
    a2 += __shfl_xor(a2, 32); a3 += __shfl_xor(a3, 32);

    a0 *= dvh; a1 *= dvh; a2 *= dvh; a3 *= dvh;

    if (doFinal) {
        if (q == 0) {   // 16 lanes: out row = (input + f1 + acc)/3, fp32
            float i0, i1, i2, i3;
            if (wid < N_USER) {
                if (isf32) {
                    float4 t4 = ((const float4*)ue)[wid * 16 + c];
                    i0 = t4.x; i1 = t4.y; i2 = t4.z; i3 = t4.w;
                } else {
                    uint2 t2 = ((const uint2*)ue)[wid * 16 + c];
                    i0 = __uint_as_float(t2.x << 16); i1 = __uint_as_float(t2.x & 0xFFFF0000u);
                    i2 = __uint_as_float(t2.y << 16); i3 = __uint_as_float(t2.y & 0xFFFF0000u);
                }
            } else {
                int w2 = wid - N_USER;
                if (isf32) {
                    float4 t4 = ((const float4*)ie)[w2 * 16 + c];
                    i0 = t4.x; i1 = t4.y; i2 = t4.z; i3 = t4.w;
                } else {
                    uint2 t2 = ((const uint2*)ie)[w2 * 16 + c];
                    i0 = __uint_as_float(t2.x << 16); i1 = __uint_as_float(t2.x & 0xFFFF0000u);
                    i2 = __uint_as_float(t2.y << 16); i3 = __uint_as_float(t2.y & 0xFFFF0000u);
                }
            }
            uint2 fr = ((const uint2*)f1b)[wid * 16 + c];
            float g0 = __uint_as_float(fr.x << 16), g1 = __uint_as_float(fr.x & 0xFFFF0000u),
                  g2 = __uint_as_float(fr.y << 16), g3 = __uint_as_float(fr.y & 0xFFFF0000u);
            const float k3 = 1.0f / 3.0f;
            ((float4*)outF)[wid * 16 + c] =
                make_float4((i0 + g0 + a0) * k3, (i1 + g1 + a1) * k3,
                            (i2 + g2 + a2) * k3, (i3 + g3 + a3) * k3);
        }
        return;
    }

    if (q == 0) {   // 16 lanes write the 128 B row
        unsigned int p01 = (unsigned int)f2bf(a0) | ((unsigned int)f2bf(a1) << 16);
        unsigned int p23 = (unsigned int)f2bf(a2) | ((unsigned int)f2bf(a3) << 16);
        ((uint2*)fach)[wid * 16 + c] = make_uint2(p01, p23);
    }

    if (writeRhn || writeTnh) {
        float ss = a0 * a0 + a1 * a1 + a2 * a2 + a3 * a3;
        ss += __shfl_xor(ss, 1); ss += __shfl_xor(ss, 2);  // reduce 4 c-lanes of factor
        float rr = 1.0f / fmaxf(sqrtf(ss), 1e-12f);
        if (writeRhn && q == 0 && (c & 3) == 0) rhn[wid * 4 + f] = rr;
        if (writeTnh) {
            float t0 = tanhf(a0 * rr), t1 = tanhf(a1 * rr),
                  t2 = tanhf(a2 * rr), t3 = tanhf(a3 * rr);
            if (q == 0) {
                unsigned int p01 = (unsigned int)f2bf(t0) | ((unsigned int)f2bf(t1) << 16);
                unsigned int p23 = (unsigned int)f2bf(t2) | ((unsigned int)f2bf(t3) << 16);
                ((uint2*)tnhOut)[wid * 16 + c] = make_uint2(p01, p23);
            }
        }
    }
}

// routing update body; no return before the internal __syncthreads
__device__ __forceinline__ void d_upd_body(
    int j, int tid, int* s_h, float (*s_p)[4],
    const unsigned short* fach, const unsigned short* tnhh,
    const float* rhn, const int* hlist, const int* tlist,
    float* P, float* dval, int first)
{
    int h = -1;
    if (j < EDGES) {
        h = hlist[j];
        int t = tlist[j];
        const uint4* frow = (const uint4*)(fach + (size_t)h * 64);
        const uint4* trow = (const uint4*)(tnhh + (size_t)t * 64);
        float d[4];
#pragma unroll 1
        for (int f = 0; f < 4; ++f) {
            uint4 a0 = frow[f * 2], a1 = frow[f * 2 + 1];
            uint4 b0 = trow[f * 2], b1 = trow[f * 2 + 1];
            d[f] = dot2(a0.x, b0.x) + dot2(a0.y, b0.y)
                 + dot2(a0.z, b0.z) + dot2(a0.w, b0.w)
                 + dot2(a1.x, b1.x) + dot2(a1.y, b1.y)
                 + dot2(a1.z, b1.z) + dot2(a1.w, b1.w);
        }
        float4 rh = ((const float4*)rhn)[h];
        float lx, ly, lz, lw;
        if (first) { lx = ly = lz = lw = -LOG4; }
        else {
            float4 p0 = ((const float4*)P)[j];
            lx = __logf(p0.x); ly = __logf(p0.y);
            lz = __logf(p0.z); lw = __logf(p0.w);
        }
        float y0 = lx + rh.x * d[0], y1 = ly + rh.y * d[1],
              y2 = lz + rh.z * d[2], y3 = lw + rh.w * d[3];
        float m = fmaxf(fmaxf(y0, y1), fmaxf(y2, y3));
        float e0 = __expf(y0 - m), e1 = __expf(y1 - m),
              e2 = __expf(y2 - m), e3 = __expf(y3 - m);
        float inv = 1.0f / (e0 + e1 + e2 + e3);
        float p0n = e0 * inv, p1n = e1 * inv, p2n = e2 * inv, p3n = e3 * inv;
        ((float4*)P)[j] = make_float4(p0n, p1n, p2n, p3n);
        s_p[tid][0] = p0n; s_p[tid][1] = p1n; s_p[tid][2] = p2n; s_p[tid][3] = p3n;
    }
    s_h[tid] = h;
    __syncthreads();
    if (h == -1) return;
    if (tid > 0 && s_h[tid - 1] == h) return;   // not a segment head
    float a0 = 0.f, a1 = 0.f, a2 = 0.f, a3 = 0.f;
    int k = tid;
    while (k < 256 && s_h[k] == h) {
        a0 += s_p[k][0]; a1 += s_p[k][1]; a2 += s_p[k][2]; a3 += s_p[k][3];
        ++k;
    }
    float* dst = dval + (size_t)h * 4;
    if (tid == 0 || k == 256) {   // may continue in adjacent block -> atomic
        unsafeAtomicAdd(dst + 0, a0);
        unsafeAtomicAdd(dst + 1, a1);
        unsafeAtomicAdd(dst + 2, a2);
        unsafeAtomicAdd(dst + 3, a3);
    } else {                      // fully interior segment -> plain store
        ((float4*)dst)[0] = make_float4(a0, a1, a2, a3);
    }
}

// ===================== shared-memory union for the megakernel =====================
union SharedU {
    struct { int s_h[256]; float s_p[256][4]; } upd;                 // 5 KB
    struct { int hist[NBUCK]; } hist;                                 // 2 KB
    struct { int red[8][32]; } btot;                                  // 1 KB
    struct { int buf[512]; } scan;                                    // 2 KB
    struct { int lg[NBUCK]; } bscat;                                  // 2 KB
    struct { int ldeg[160]; int lcur[160]; int sbuf[256]; } bfin;     // 2.3 KB
};

// ===================== cooperative megakernel =====================
__global__ void __launch_bounds__(256, 8)
k_mega(const void* ue, const void* ie, const int* hl, const int* tl,
       float* outF, float* P, int* cnt, int* gbase, int* bt,
       float* dvA, float* dvB, float* rhn,
       unsigned short* bufW, unsigned short* bufX, unsigned short* bufY,
       unsigned short* bufZ0, unsigned short* bufZ1,
       int* boff, int* btot, int* off, int* tlist, int* hlist)
{
    cg::grid_group grid = cg::this_grid();
    __shared__ SharedU sh;
    int tid = threadIdx.x, bid = blockIdx.x, nb = gridDim.x;
    int lane = tid & 63, warp = tid >> 6;

    // ---- per-block dtype detect (block-uniform, no global flag) ----
    int cdet = 0;
    {
        const unsigned short* raw = (const unsigned short*)ue;
        for (int i = tid; i < 16384; i += 256) {
            unsigned short u = raw[i];
            if ((u & 0x7F80) == 0x7F80) cdet++;
        }
        sh.scan.buf[tid] = cdet;
        __syncthreads();
        for (int s = 128; s > 0; s >>= 1) {
            if (tid < s) sh.scan.buf[tid] += sh.scan.buf[tid + s];
            __syncthreads();
        }
        cdet = sh.scan.buf[0];
        __syncthreads();
    }
    int isf32 = (cdet > 0);

    // ---- init: ego bf16 + tnh0 ----
    for (int vb = bid; vb < 20000; vb += nb)
        d_init_body(vb * 4 + warp, lane, ue, ie, isf32, bufW, bufZ0);

    // ---- CSR phase A: per-chunk histograms ----
    for (int vb = bid; vb < BBLK; vb += nb)
        d_bcnt_body(vb, tid, sh.hist.hist, hl, cnt);
    grid.sync();

    // ---- CSR phase A2a: bucket totals (16 vbs x 32 buckets, 8 b-slices) ----
    for (int vb = bid; vb < 16; vb += nb) {
        int kk = tid & 31, sl = tid >> 5;
        int k = vb * 32 + kk;
        int s = 0;
        for (int b = sl; b < BBLK; b += 8) s += cnt[b * NBUCK + k];
        sh.btot.red[sl][kk] = s;
        __syncthreads();
        if (sl == 0) {
            int tot = 0;
#pragma unroll
            for (int x = 0; x < 8; ++x) tot += sh.btot.red[x][kk];
            btot[k] = tot;
        }
        __syncthreads();
    }
    grid.sync();

    // ---- CSR phase A2b: exclusive scan of btot -> boff (block 0) ----
    if (bid == 0) {
        int v0 = btot[tid], v1 = btot[tid + 256];
        sh.scan.buf[tid] = v0; sh.scan.buf[tid + 256] = v1;
        __syncthreads();
        for (int s = 1; s < 512; s <<= 1) {
            int t0 = (tid >= s) ? sh.scan.buf[tid - s] : 0;
            int t1 = sh.scan.buf[tid + 256 - s];
            __syncthreads();
            sh.scan.buf[tid] += t0;
            sh.scan.buf[tid + 256] += t1;
            __syncthreads();
        }
        boff[tid] = sh.scan.buf[tid] - v0;
        boff[tid + 256] = sh.scan.buf[tid + 256] - v1;
        if (tid == 0) boff[NBUCK] = EDGES;
    }
    grid.sync();

    // ---- CSR phase B: per-bucket scan over chunk blocks -> gbase ----
    for (int vb = bid; vb < NBUCK; vb += nb) {
        int k = vb;
        int v0 = cnt[tid * NBUCK + k];
        int v1 = cnt[(tid + 256) * NBUCK + k];
        sh.scan.buf[tid] = v0; sh.scan.buf[tid + 256] = v1;
        __syncthreads();
        for (int s = 1; s < 512; s <<= 1) {
            int t0 = (tid >= s) ? sh.scan.buf[tid - s] : 0;
            int t1 = sh.scan.buf[tid + 256 - s];
            __syncthreads();
            sh.scan.buf[tid] += t0;
            sh.scan.buf[tid + 256] += t1;
            __syncthreads();
        }
        int bo = boff[k];
        gbase[tid * NBUCK + k] = bo + sh.scan.buf[tid] - v0;
        gbase[(tid + 256) * NBUCK + k] = bo + sh.scan.buf[tid + 256] - v1;
        __syncthreads();
    }
    grid.sync();

    // ---- CSR phase C: bucketize ----
    for (int vb = bid; vb < BBLK; vb += nb)
        d_bscat_body(vb, tid, sh.bscat.lg, hl, tl, gbase, bt);
    grid.sync();

    // ---- CSR phase D: finalize (off, dvA seed, tlist, hlist) ----
    for (int vb = bid; vb < NBUCK; vb += nb)
        d_bfin_body(vb, tid, sh.bfin.ldeg, sh.bfin.lcur, sh.bfin.sbuf,
                    bt, boff, off, dvA, tlist, hlist);
    grid.sync();

    // ---- layer 0, iter 0: mp0 -> f0=X ----
    for (int vb = bid; vb < 20000; vb += nb)
        d_mp_body(vb * 4 + warp, lane, bufW, P, dvA, dvB, off, tlist,
                  bufX, rhn, bufZ1, bufY, ue, ie, isf32, outF, 0, 1, 0, 0);
    grid.sync();
    for (int vb = bid; vb < 3907; vb += nb) {
        d_upd_body(vb * 256 + tid, tid, sh.upd.s_h, sh.upd.s_p,
                   bufX, bufZ0, rhn, hlist, tlist, P, dvB, 1);
        __syncthreads();
    }
    grid.sync();

    // ---- layer 0, iter 1: mp1 -> f1=Y (+tnh1) ----
    for (int vb = bid; vb < 20000; vb += nb)
        d_mp_body(vb * 4 + warp, lane, bufW, P, dvB, dvA, off, tlist,
                  bufY, rhn, bufZ1, bufY, ue, ie, isf32, outF, 1, 1, 1, 0);
    grid.sync();
    for (int vb = bid; vb < 3907; vb += nb) {
        d_upd_body(vb * 256 + tid, tid, sh.upd.s_h, sh.upd.s_p,
                   bufY, bufZ0, rhn, hlist, tlist, P, dvA, 0);
        __syncthreads();
    }
    grid.sync();

    // ---- layer 1, iter 0: mp2 -> f2=X ----
    for (int vb = bid; vb < 20000; vb += nb)
        d_mp_body(vb * 4 + warp, lane, bufY, P, dvA, dvB, off, tlist,
                  bufX, rhn, bufZ1, bufY, ue, ie, isf32, outF, 1, 1, 0, 0);
    grid.sync();
    for (int vb = bid; vb < 3907; vb += nb) {
        d_upd_body(vb * 256 + tid, tid, sh.upd.s_h, sh.upd.s_p,
                   bufX, bufZ1, rhn, hlist, tlist, P, dvB, 0);
        __syncthreads();
    }
    grid.sync();

    // ---- layer 1, iter 1: mp3 -> fused final out ----
    for (int vb = bid; vb < 20000; vb += nb)
        d_mp_body(vb * 4 + warp, lane, bufY, P, dvB, nullptr, off, tlist,
                  bufX, rhn, bufZ1, bufY, ue, ie, isf32, outF, 1, 0, 0, 1);
}

// ===================== fallback kernels (round-6 path) =====================

__global__ void k_detect(const unsigned short* __restrict__ raw, int* __restrict__ flag) {
    __shared__ int s;
    if (threadIdx.x == 0) s = 0;
    __syncthreads();
    int c = 0;
    for (int i = threadIdx.x; i < 16384; i += 256) {
        unsigned short u = raw[i];
        if ((u & 0x7F80) == 0x7F80) c++;
    }
    atomicAdd(&s, c);
    __syncthreads();
    if (threadIdx.x == 0) *flag = (s > 0) ? 1 : 0;  // 1 => fp32
}

__global__ void k_init(const void* ue, const void* ie, const int* __restrict__ flag,
                       unsigned short* egoh, unsigned short* tnh0) {
    int gid = blockIdx.x * blockDim.x + threadIdx.x;
    int wid = gid >> 6;
    int lane = threadIdx.x & 63;
    d_init_body(wid, lane, ue, ie, (*flag != 0), egoh, tnh0);
}

__global__ void k_bcnt(const int* __restrict__ hl, int* __restrict__ cnt) {
    __shared__ int hist[NBUCK];
    d_bcnt_body(blockIdx.x, threadIdx.x, hist, hl, cnt);
}

__global__ void k_btot(const int* __restrict__ cnt, int* __restrict__ boff) {
    __shared__ int sbuf[NBUCK];
    int k = threadIdx.x;
    int s = 0;
    for (int b = 0; b < BBLK; ++b) s += cnt[b * NBUCK + k];
    sbuf[k] = s;
    __syncthreads();
    int v = s;
    for (int st = 1; st < NBUCK; st <<= 1) {
        int t = (k >= st) ? sbuf[k - st] : 0;
        __syncthreads();
        sbuf[k] += t;
        __syncthreads();
    }
    boff[k] = sbuf[k] - v;
    if (k == NBUCK - 1) boff[NBUCK] = EDGES;
}

__global__ void k_bscan(const int* __restrict__ cnt, const int* __restrict__ boff,
                        int* __restrict__ gbase) {
    __shared__ int buf[BBLK];
    int k = blockIdx.x, tid = threadIdx.x;  // 512 threads, tid = block index b
    int v = cnt[tid * NBUCK + k];
    buf[tid] = v;
    __syncthreads();
    for (int s = 1; s < BBLK; s <<= 1) {
        int t = (tid >= s) ? buf[tid - s] : 0;
        __syncthreads();
        buf[tid] += t;
        __syncthreads();
    }
    gbase[tid * NBUCK + k] = boff[k] + buf[tid] - v;
}

__global__ void k_bscat(const int* __restrict__ hl, const int* __restrict__ tl,
                        const int* __restrict__ gbase, int* __restrict__ bt) {
    __shared__ int lg[NBUCK];
    d_bscat_body(blockIdx.x, threadIdx.x, lg, hl, tl, gbase, bt);
}

__global__ void k_bfin(const int* __restrict__ bt, const int* __restrict__ boff,
                       int* __restrict__ off, float* __restrict__ dvacc,
                       int* __restrict__ tlist, int* __restrict__ hlist) {
    __shared__ int ldeg[160];
    __shared__ int lcur[160];
    __shared__ int sbuf[256];
    d_bfin_body(blockIdx.x, threadIdx.x, ldeg, lcur, sbuf, bt, boff, off, dvacc,
                tlist, hlist);
}

__global__ void k_mp(const unsigned short* ego, const float* P,
                     const float* dva, float* zb,
                     const int* off, const int* tlist,
                     unsigned short* fach, float* rhn, unsigned short* tnhOut,
                     const unsigned short* f1b,
                     const void* ue, const void* ie,
                     const int* __restrict__ flag, float* outF,
                     int useP, int writeRhn, int writeTnh, int doFinal) {
    int gid = blockIdx.x * blockDim.x + threadIdx.x;
    int wid = gid >> 6;
    int lane = threadIdx.x & 63;
    int isf32 = doFinal ? (*flag != 0) : 0;
    d_mp_body(wid, lane, ego, P, dva, zb, off, tlist, fach, rhn, tnhOut,
              f1b, ue, ie, isf32, outF, useP, writeRhn, writeTnh, doFinal);
}

__global__ void k_upd(const unsigned short* fach, const unsigned short* tnhh,
                      const float* rhn, const int* hlist, const int* tlist,
                      float* P, float* dval, int first) {
    __shared__ int   s_h[256];
    __shared__ float s_p[256][4];
    d_upd_body(blockIdx.x * 256 + threadIdx.x, threadIdx.x, s_h, s_p,
               fach, tnhh, rhn, hlist, tlist, P, dval, first);
}

// ===================== host =====================

extern "C" void kernel_launch(void* const* d_in, const int* in_sizes, int n_in,
                              void* d_out, int out_size, void* d_ws, size_t ws_size,
                              hipStream_t stream) {
    const void* ue = d_in[0];
    const void* ie = d_in[1];
    const int* hl = (const int*)d_in[2];
    const int* tl = (const int*)d_in[3];
    float* out = (float*)d_out;

    float* ws    = (float*)d_ws;
    float* P     = ws;
    int*   bt    = (int*)(ws);              // overlaps P (dead before P first written)
    int*   cnt   = (int*)(ws + 1000000);    // overlaps P
    int*   gbase = (int*)(ws + 1262144);    // overlaps P
    float* dvA   = ws + 4000000;
    float* dvB   = ws + 4320000;
    float* rhn   = ws + 4640000;
    unsigned short* bufW = (unsigned short*)(ws + 4960000);   // input ego (bf16)
    unsigned short* bufX = (unsigned short*)(ws + 7520000);   // f0 / f2
    unsigned short* bufY = (unsigned short*)(ws + 10080000);  // f1 (layer-1 input)
    unsigned short* bufZ0 = (unsigned short*)(ws + 12640000); // layer-0 tnh
    unsigned short* bufZ1 = (unsigned short*)(ws + 15200000); // layer-1 tnh
    int*   flag = (int*)(ws + 20320000);
    int*   boff = (int*)(ws + 20320016);    // 513 ints (bucket bases)
    int*   btotp = (int*)(ws + 20321000);   // 512 ints (bucket totals, mega only)
    int*   off  = (int*)(ws + 20400016);
    int*   tlist = (int*)(ws + 20480017);
    int*   hlist = (int*)(ws + 21480017);

    void* kargs[] = { (void*)&ue, (void*)&ie, (void*)&hl, (void*)&tl,
                      (void*)&out, (void*)&P, (void*)&cnt, (void*)&gbase, (void*)&bt,
                      (void*)&dvA, (void*)&dvB, (void*)&rhn,
                      (void*)&bufW, (void*)&bufX, (void*)&bufY,
                      (void*)&bufZ0, (void*)&bufZ1,
                      (void*)&boff, (void*)&btotp, (void*)&off,
                      (void*)&tlist, (void*)&hlist };
    hipError_t err = hipLaunchCooperativeKernel((const void*)k_mega, dim3(GRID),
                                                dim3(256), kargs, 0, stream);
    if (err == hipSuccess) return;
    (void)hipGetLastError();   // clear error state; fall back to multi-kernel path

    k_detect<<<1, 256, 0, stream>>>((const unsigned short*)ue, flag);
    k_init<<<20000, 256, 0, stream>>>(ue, ie, flag, bufW, bufZ0);

    k_bcnt<<<BBLK, 256, 0, stream>>>(hl, cnt);
    k_btot<<<1, NBUCK, 0, stream>>>(cnt, boff);
    k_bscan<<<NBUCK, BBLK, 0, stream>>>(cnt, boff, gbase);
    k_bscat<<<BBLK, 256, 0, stream>>>(hl, tl, gbase, bt);
    k_bfin<<<NBUCK, 256, 0, stream>>>(bt, boff, off, dvA, tlist, hlist);

    // layer 0 (ego = bufW)
    k_mp<<<20000, 256, 0, stream>>>(bufW, P, dvA, dvB, off, tlist, bufX, rhn, bufZ1,
                                    bufY, ue, ie, flag, out, 0, 1, 0, 0);
    k_upd<<<3907, 256, 0, stream>>>(bufX, bufZ0, rhn, hlist, tlist, P, dvB, 1);
    k_mp<<<20000, 256, 0, stream>>>(bufW, P, dvB, dvA, off, tlist, bufY, rhn, bufZ1,
                                    bufY, ue, ie, flag, out, 1, 1, 1, 0);
    k_upd<<<3907, 256, 0, stream>>>(bufY, bufZ0, rhn, hlist, tlist, P, dvA, 0);
    // layer 1 (ego = bufY)
    k_mp<<<20000, 256, 0, stream>>>(bufY, P, dvA, dvB, off, tlist, bufX, rhn, bufZ1,
                                    bufY, ue, ie, flag, out, 1, 1, 0, 0);
    k_upd<<<3907, 256, 0, stream>>>(bufX, bufZ1, rhn, hlist, tlist, P, dvB, 0);
    k_mp<<<20000, 256, 0, stream>>>(bufY, P, dvB, nullptr, off, tlist, bufX, rhn, bufZ1,
                                    bufY, ue, ie, flag, out, 1, 0, 0, 1);
}

// Round 8
// 391.394 us; speedup vs baseline: 8.8454x; 8.8454x over previous
//
#include <hip/hip_runtime.h>
#include <hip/hip_bf16.h>

#define N_USER 50000
#define N_ITEM 30000
#define NTOT   80000
#define EMB    64
#define FAC    4
#define EDGES  1000000
#define LOG4   1.3862943611198906f
#define NBUCK  512   // h-buckets for CSR build
#define BBLK   512   // blocks in count/scatter phases
#define BCH    1954  // ceil(EDGES/BBLK)

// ws layout (float idx), ~90 MB:
//   P     +0          4,000,000  (softmax probs; overlapped early by bt/cnt/gbase —
//                                 all dead before P first written in upd0)
//   dvA   +4,000,000    320,000  (dval ping; seeded 0.25*deg by bfin)
//   dvB   +4,320,000    320,000  (dval pong)
//   rhn   +4,640,000    320,000
//   bufW  +4,960,000  2,560,000  (bf16: input ego)
//   bufX  +7,520,000  2,560,000  (bf16: f0 / f2)
//   bufY  +10,080,000 2,560,000  (bf16: f1 = layer-1 input)
//   bufZ0 +12,640,000 2,560,000  (bf16: layer-0 tanh-norm)
//   bufZ1 +15,200,000 2,560,000  (bf16: layer-1 tanh-norm)
//   flag  +20,320,000 16 | boff +20,320,016 513
//   off   +20,400,016 80,001
//   tlist +20,480,017 1,000,000 | hlist +21,480,017 1,000,000

__device__ inline float bf2f(unsigned short u) {
    return __uint_as_float(((unsigned int)u) << 16);
}
__device__ inline unsigned short f2bf(float f) {
    unsigned int x = __float_as_uint(f);
    x += 0x7FFFu + ((x >> 16) & 1u);       // round-to-nearest-even
    return (unsigned short)(x >> 16);
}
__device__ inline float dot2(unsigned int a, unsigned int b) {
    float a0 = __uint_as_float(a << 16), a1 = __uint_as_float(a & 0xFFFF0000u);
    float b0 = __uint_as_float(b << 16), b1 = __uint_as_float(b & 0xFFFF0000u);
    return a0 * b0 + a1 * b1;
}
__device__ inline int bucket_of(int h) { return (int)(((unsigned)h * NBUCK) / (unsigned)NTOT); }
__device__ inline int bucket_lo(int k) { return (k * NTOT + NBUCK - 1) / NBUCK; }

// ---- input dtype detector (fp32 read-as-bf16 shows inf/NaN bit patterns) ----
__global__ void k_detect(const unsigned short* __restrict__ raw, int* __restrict__ flag) {
    __shared__ int s;
    if (threadIdx.x == 0) s = 0;
    __syncthreads();
    int c = 0;
    for (int i = threadIdx.x; i < 16384; i += 256) {
        unsigned short u = raw[i];
        if ((u & 0x7F80) == 0x7F80) c++;
    }
    atomicAdd(&s, c);
    __syncthreads();
    if (threadIdx.x == 0) *flag = (s > 0) ? 1 : 0;  // 1 => fp32
}

// ---- init: ego(bf16) + layer-0 tnh ----
__global__ void k_init(const void* __restrict__ ue, const void* __restrict__ ie,
                       const int* __restrict__ flag,
                       unsigned short* __restrict__ egoh,
                       unsigned short* __restrict__ tnh0) {
    int gid = blockIdx.x * blockDim.x + threadIdx.x;
    int wid = gid >> 6;
    int lane = threadIdx.x & 63;
    if (wid >= NTOT) return;
    int i = wid * 64 + lane;
    bool isf32 = (*flag != 0);
    float v;
    if (i < N_USER * EMB) {
        v = isf32 ? ((const float*)ue)[i]
                  : __bfloat162float(((const __hip_bfloat16*)ue)[i]);
    } else {
        int j = i - N_USER * EMB;
        v = isf32 ? ((const float*)ie)[j]
                  : __bfloat162float(((const __hip_bfloat16*)ie)[j]);
    }
    egoh[i] = f2bf(v);
    float ss = v * v;
    ss += __shfl_xor(ss, 1); ss += __shfl_xor(ss, 2);
    ss += __shfl_xor(ss, 4); ss += __shfl_xor(ss, 8);
    float rr = 1.0f / fmaxf(sqrtf(ss), 1e-12f);
    tnh0[i] = f2bf(tanhf(v * rr));
}

// ---- CSR build via bucket sort (single-writer windows; no global atomics) ----
__global__ void k_bcnt(const int* __restrict__ hl, int* __restrict__ cnt) {
    __shared__ int hist[NBUCK];
    int b = blockIdx.x, tid = threadIdx.x;
    for (int i = tid; i < NBUCK; i += 256) hist[i] = 0;
    __syncthreads();
    int base = b * BCH, end = base + BCH; if (end > EDGES) end = EDGES;
    for (int e = base + tid; e < end; e += 256)
        atomicAdd(&hist[bucket_of(hl[e])], 1);
    __syncthreads();
    for (int i = tid; i < NBUCK; i += 256) cnt[b * NBUCK + i] = hist[i];
}

__global__ void k_btot(const int* __restrict__ cnt, int* __restrict__ boff) {
    __shared__ int sbuf[NBUCK];
    int k = threadIdx.x;
    int s = 0;
    for (int b = 0; b < BBLK; ++b) s += cnt[b * NBUCK + k];
    sbuf[k] = s;
    __syncthreads();
    int v = s;
    for (int st = 1; st < NBUCK; st <<= 1) {
        int t = (k >= st) ? sbuf[k - st] : 0;
        __syncthreads();
        sbuf[k] += t;
        __syncthreads();
    }
    boff[k] = sbuf[k] - v;
    if (k == NBUCK - 1) boff[NBUCK] = EDGES;
}

__global__ void k_bscan(const int* __restrict__ cnt, const int* __restrict__ boff,
                        int* __restrict__ gbase) {
    __shared__ int buf[BBLK];
    int k = blockIdx.x, tid = threadIdx.x;  // 512 threads, tid = block index b
    int v = cnt[tid * NBUCK + k];
    buf[tid] = v;
    __syncthreads();
    for (int s = 1; s < BBLK; s <<= 1) {
        int t = (tid >= s) ? buf[tid - s] : 0;
        __syncthreads();
        buf[tid] += t;
        __syncthreads();
    }
    gbase[tid * NBUCK + k] = boff[k] + buf[tid] - v;
}

__global__ void k_bscat(const int* __restrict__ hl, const int* __restrict__ tl,
                        const int* __restrict__ gbase, int* __restrict__ bt) {
    __shared__ int lg[NBUCK];
    int b = blockIdx.x, tid = threadIdx.x;
    for (int i = tid; i < NBUCK; i += 256) lg[i] = gbase[b * NBUCK + i];
    __syncthreads();
    int base = b * BCH, end = base + BCH; if (end > EDGES) end = EDGES;
    for (int e = base + tid; e < end; e += 256) {
        int h = hl[e];
        int k = bucket_of(h);
        int pos = atomicAdd(&lg[k], 1);
        bt[pos] = ((h - bucket_lo(k)) << 17) | tl[e];
    }
}

__global__ void k_bfin(const int* __restrict__ bt, const int* __restrict__ boff,
                       int* __restrict__ off, float* __restrict__ dvacc,
                       int* __restrict__ tlist, int* __restrict__ hlist) {
    __shared__ int ldeg[160];
    __shared__ int lcur[160];
    __shared__ int sbuf[256];
    int k = blockIdx.x, tid = threadIdx.x;
    int lo = bucket_lo(k), hi = bucket_lo(k + 1);
    int nn = hi - lo;                 // 156 or 157
    for (int i = tid; i < nn; i += 256) ldeg[i] = 0;
    __syncthreads();
    int start = boff[k], end = boff[k + 1];
    for (int j = start + tid; j < end; j += 256)
        atomicAdd(&ldeg[bt[j] >> 17], 1);
    __syncthreads();
    int v = (tid < nn) ? ldeg[tid] : 0;
    sbuf[tid] = v;
    __syncthreads();
    for (int s = 1; s < 256; s <<= 1) {
        int t = (tid >= s) ? sbuf[tid - s] : 0;
        __syncthreads();
        sbuf[tid] += t;
        __syncthreads();
    }
    if (tid < nn) {
        int o = start + sbuf[tid] - v;
        off[lo + tid] = o;
        lcur[tid] = o;
        float d = 0.25f * (float)v;
        ((float4*)dvacc)[lo + tid] = make_float4(d, d, d, d);
    }
    if (k == 0 && tid == 0) off[NTOT] = EDGES;
    __syncthreads();
    for (int j = start + tid; j < end; j += 256) {
        int val = bt[j];
        int hrel = val >> 17;
        int t = val & 0x1FFFF;
        int pos = atomicAdd(&lcur[hrel], 1);
        tlist[pos] = t;
        hlist[pos] = lo + hrel;
    }
}

// ---- message passing: acc += w * dvt * ego[t]; w = P or 0.25; dv from dva ----
// Wide layout: lane = q*8 + c; q = edge slot (8 edges in flight), c = col-group
// (cols 8c..8c+7, factor f = c>>1). Each lane gathers uint4 (8 bf16, 16 B).
// 8 lanes cover a 128 B row; avg degree 12.5 -> ~1.6 loop trips per node.
// dva = current dval buffer (rsqrt in-register). zb = next dval buffer to
// prezero (ping-pong; null on last pass).
// doFinal (pass 3): instead of writing fach, emit out = (input + f1 + acc)/3.
__global__ void k_mp(const unsigned short* __restrict__ ego, const float* __restrict__ P,
                     const float* __restrict__ dva, float* __restrict__ zb,
                     const int* __restrict__ off, const int* __restrict__ tlist,
                     unsigned short* __restrict__ fach, float* __restrict__ rhn,
                     unsigned short* __restrict__ tnhOut,
                     const unsigned short* __restrict__ f1b,
                     const void* __restrict__ ue, const void* __restrict__ ie,
                     const int* __restrict__ flag, float* __restrict__ outF,
                     int useP, int writeRhn, int writeTnh, int doFinal) {
    int gid = blockIdx.x * blockDim.x + threadIdx.x;
    int wid = gid >> 6;
    int lane = threadIdx.x & 63;
    if (wid >= NTOT) return;
    int c = lane & 7;    // column group: cols 8c..8c+7
    int q = lane >> 3;   // edge slot (0..7)
    int f = c >> 1;      // factor of these columns
    if (zb != nullptr && lane < 4) zb[wid * 4 + lane] = 0.f;   // prezero next dval
    int beg = off[wid], end = off[wid + 1];
    float dvh = rsqrtf(fmaxf(dva[wid * 4 + f], 1e-8f));
    const uint4* eg4 = (const uint4*)ego;   // one row = 8 uint4 (128 B)

    float a0 = 0.f, a1 = 0.f, a2 = 0.f, a3 = 0.f;
    float a4 = 0.f, a5 = 0.f, a6 = 0.f, a7 = 0.f;
    int nfull = (end - beg) >> 3;
    int j = beg + q;
    if (useP) {
#pragma unroll 2
        for (int g = 0; g < nfull; ++g, j += 8) {
            int t = tlist[j];
            float w = P[j * 4 + f];
            float dvt = rsqrtf(fmaxf(dva[t * 4 + f], 1e-8f));
            uint4 u = eg4[(size_t)t * 8 + c];
            w *= dvt;
            a0 += w * __uint_as_float(u.x << 16);
            a1 += w * __uint_as_float(u.x & 0xFFFF0000u);
            a2 += w * __uint_as_float(u.y << 16);
            a3 += w * __uint_as_float(u.y & 0xFFFF0000u);
            a4 += w * __uint_as_float(u.z << 16);
            a5 += w * __uint_as_float(u.z & 0xFFFF0000u);
            a6 += w * __uint_as_float(u.w << 16);
            a7 += w * __uint_as_float(u.w & 0xFFFF0000u);
        }
        if (j < end) {   // tail: 1-7 edges, exec-masked
            int t = tlist[j];
            float w = P[j * 4 + f];
            float dvt = rsqrtf(fmaxf(dva[t * 4 + f], 1e-8f));
            uint4 u = eg4[(size_t)t * 8 + c];
            w *= dvt;
            a0 += w * __uint_as_float(u.x << 16);
            a1 += w * __uint_as_float(u.x & 0xFFFF0000u);
            a2 += w * __uint_as_float(u.y << 16);
            a3 += w * __uint_as_float(u.y & 0xFFFF0000u);
            a4 += w * __uint_as_float(u.z << 16);
            a5 += w * __uint_as_float(u.z & 0xFFFF0000u);
            a6 += w * __uint_as_float(u.w << 16);
            a7 += w * __uint_as_float(u.w & 0xFFFF0000u);
        }
    } else {
#pragma unroll 2
        for (int g = 0; g < nfull; ++g, j += 8) {
            int t = tlist[j];
            float dvt = rsqrtf(fmaxf(dva[t * 4 + f], 1e-8f));
            uint4 u = eg4[(size_t)t * 8 + c];
            float w = 0.25f * dvt;
            a0 += w * __uint_as_float(u.x << 16);
            a1 += w * __uint_as_float(u.x & 0xFFFF0000u);
            a2 += w * __uint_as_float(u.y << 16);
            a3 += w * __uint_as_float(u.y & 0xFFFF0000u);
            a4 += w * __uint_as_float(u.z << 16);
            a5 += w * __uint_as_float(u.z & 0xFFFF0000u);
            a6 += w * __uint_as_float(u.w << 16);
            a7 += w * __uint_as_float(u.w & 0xFFFF0000u);
        }
        if (j < end) {
            int t = tlist[j];
            float dvt = rsqrtf(fmaxf(dva[t * 4 + f], 1e-8f));
            uint4 u = eg4[(size_t)t * 8 + c];
            float w = 0.25f * dvt;
            a0 += w * __uint_as_float(u.x << 16);
            a1 += w * __uint_as_float(u.x & 0xFFFF0000u);
            a2 += w * __uint_as_float(u.y << 16);
            a3 += w * __uint_as_float(u.y & 0xFFFF0000u);
            a4 += w * __uint_as_float(u.z << 16);
            a5 += w * __uint_as_float(u.z & 0xFFFF0000u);
            a6 += w * __uint_as_float(u.w << 16);
            a7 += w * __uint_as_float(u.w & 0xFFFF0000u);
        }
    }

    // combine the 8 edge slots (lane bits 3,4,5)
    a0 += __shfl_xor(a0, 8);  a1 += __shfl_xor(a1, 8);
    a2 += __shfl_xor(a2, 8);  a3 += __shfl_xor(a3, 8);
    a4 += __shfl_xor(a4, 8);  a5 += __shfl_xor(a5, 8);
    a6 += __shfl_xor(a6, 8);  a7 += __shfl_xor(a7, 8);
    a0 += __shfl_xor(a0, 16); a1 += __shfl_xor(a1, 16);
    a2 += __shfl_xor(a2, 16); a3 += __shfl_xor(a3, 16);
    a4 += __shfl_xor(a4, 16); a5 += __shfl_xor(a5, 16);
    a6 += __shfl_xor(a6, 16); a7 += __shfl_xor(a7, 16);
    a0 += __shfl_xor(a0, 32); a1 += __shfl_xor(a1, 32);
    a2 += __shfl_xor(a2, 32); a3 += __shfl_xor(a3, 32);
    a4 += __shfl_xor(a4, 32); a5 += __shfl_xor(a5, 32);
    a6 += __shfl_xor(a6, 32); a7 += __shfl_xor(a7, 32);

    a0 *= dvh; a1 *= dvh; a2 *= dvh; a3 *= dvh;
    a4 *= dvh; a5 *= dvh; a6 *= dvh; a7 *= dvh;

    if (doFinal) {
        if (q == 0) {   // 8 lanes: out row = (input + f1 + acc)/3, fp32 (8 cols/lane)
            bool isf32 = (*flag != 0);
            float i0, i1, i2, i3, i4, i5, i6, i7;
            if (wid < N_USER) {
                if (isf32) {
                    float4 t4 = ((const float4*)ue)[wid * 16 + c * 2];
                    float4 t5 = ((const float4*)ue)[wid * 16 + c * 2 + 1];
                    i0 = t4.x; i1 = t4.y; i2 = t4.z; i3 = t4.w;
                    i4 = t5.x; i5 = t5.y; i6 = t5.z; i7 = t5.w;
                } else {
                    uint4 t2 = ((const uint4*)ue)[wid * 8 + c];
                    i0 = __uint_as_float(t2.x << 16); i1 = __uint_as_float(t2.x & 0xFFFF0000u);
                    i2 = __uint_as_float(t2.y << 16); i3 = __uint_as_float(t2.y & 0xFFFF0000u);
                    i4 = __uint_as_float(t2.z << 16); i5 = __uint_as_float(t2.z & 0xFFFF0000u);
                    i6 = __uint_as_float(t2.w << 16); i7 = __uint_as_float(t2.w & 0xFFFF0000u);
                }
            } else {
                int w2 = wid - N_USER;
                if (isf32) {
                    float4 t4 = ((const float4*)ie)[w2 * 16 + c * 2];
                    float4 t5 = ((const float4*)ie)[w2 * 16 + c * 2 + 1];
                    i0 = t4.x; i1 = t4.y; i2 = t4.z; i3 = t4.w;
                    i4 = t5.x; i5 = t5.y; i6 = t5.z; i7 = t5.w;
                } else {
                    uint4 t2 = ((const uint4*)ie)[w2 * 8 + c];
                    i0 = __uint_as_float(t2.x << 16); i1 = __uint_as_float(t2.x & 0xFFFF0000u);
                    i2 = __uint_as_float(t2.y << 16); i3 = __uint_as_float(t2.y & 0xFFFF0000u);
                    i4 = __uint_as_float(t2.z << 16); i5 = __uint_as_float(t2.z & 0xFFFF0000u);
                    i6 = __uint_as_float(t2.w << 16); i7 = __uint_as_float(t2.w & 0xFFFF0000u);
                }
            }
            uint4 fr = ((const uint4*)f1b)[wid * 8 + c];
            float g0 = __uint_as_float(fr.x << 16), g1 = __uint_as_float(fr.x & 0xFFFF0000u),
                  g2 = __uint_as_float(fr.y << 16), g3 = __uint_as_float(fr.y & 0xFFFF0000u),
                  g4 = __uint_as_float(fr.z << 16), g5 = __uint_as_float(fr.z & 0xFFFF0000u),
                  g6 = __uint_as_float(fr.w << 16), g7 = __uint_as_float(fr.w & 0xFFFF0000u);
            const float k3 = 1.0f / 3.0f;
            ((float4*)outF)[wid * 16 + c * 2] =
                make_float4((i0 + g0 + a0) * k3, (i1 + g1 + a1) * k3,
                            (i2 + g2 + a2) * k3, (i3 + g3 + a3) * k3);
            ((float4*)outF)[wid * 16 + c * 2 + 1] =
                make_float4((i4 + g4 + a4) * k3, (i5 + g5 + a5) * k3,
                            (i6 + g6 + a6) * k3, (i7 + g7 + a7) * k3);
        }
        return;
    }

    if (q == 0) {   // 8 lanes write the 128 B row
        unsigned int p0 = (unsigned int)f2bf(a0) | ((unsigned int)f2bf(a1) << 16);
        unsigned int p1 = (unsigned int)f2bf(a2) | ((unsigned int)f2bf(a3) << 16);
        unsigned int p2 = (unsigned int)f2bf(a4) | ((unsigned int)f2bf(a5) << 16);
        unsigned int p3 = (unsigned int)f2bf(a6) | ((unsigned int)f2bf(a7) << 16);
        ((uint4*)fach)[wid * 8 + c] = make_uint4(p0, p1, p2, p3);
    }

    if (writeRhn || writeTnh) {
        float ss = a0 * a0 + a1 * a1 + a2 * a2 + a3 * a3
                 + a4 * a4 + a5 * a5 + a6 * a6 + a7 * a7;
        ss += __shfl_xor(ss, 1);   // combine the factor's 2 c-lanes (16 dims)
        float rr = 1.0f / fmaxf(sqrtf(ss), 1e-12f);
        if (writeRhn && q == 0 && (c & 1) == 0) rhn[wid * 4 + f] = rr;
        if (writeTnh) {
            float t0 = tanhf(a0 * rr), t1 = tanhf(a1 * rr),
                  t2 = tanhf(a2 * rr), t3 = tanhf(a3 * rr),
                  t4 = tanhf(a4 * rr), t5 = tanhf(a5 * rr),
                  t6 = tanhf(a6 * rr), t7 = tanhf(a7 * rr);
            if (q == 0) {
                unsigned int p0 = (unsigned int)f2bf(t0) | ((unsigned int)f2bf(t1) << 16);
                unsigned int p1 = (unsigned int)f2bf(t2) | ((unsigned int)f2bf(t3) << 16);
                unsigned int p2 = (unsigned int)f2bf(t4) | ((unsigned int)f2bf(t5) << 16);
                unsigned int p3 = (unsigned int)f2bf(t6) | ((unsigned int)f2bf(t7) << 16);
                ((uint4*)tnhOut)[wid * 8 + c] = make_uint4(p0, p1, p2, p3);
            }
        }
    }
}

// ---- routing update + fused dval via CSR-contiguous segmented reduction ----
__global__ void k_upd(const unsigned short* __restrict__ fach,
                      const unsigned short* __restrict__ tnhh,
                      const float* __restrict__ rhn,
                      const int* __restrict__ hlist, const int* __restrict__ tlist,
                      float* __restrict__ P, float* __restrict__ dval, int first) {
    __shared__ int   s_h[256];
    __shared__ float s_p[256][4];
    int tid = threadIdx.x;
    int j = blockIdx.x * 256 + tid;
    int h = -1;
    if (j < EDGES) {
        h = hlist[j];
        int t = tlist[j];
        const uint4* frow = (const uint4*)(fach + (size_t)h * 64);
        const uint4* trow = (const uint4*)(tnhh + (size_t)t * 64);
        float d[4];
#pragma unroll
        for (int f = 0; f < 4; ++f) {
            uint4 a0 = frow[f * 2], a1 = frow[f * 2 + 1];
            uint4 b0 = trow[f * 2], b1 = trow[f * 2 + 1];
            d[f] = dot2(a0.x, b0.x) + dot2(a0.y, b0.y)
                 + dot2(a0.z, b0.z) + dot2(a0.w, b0.w)
                 + dot2(a1.x, b1.x) + dot2(a1.y, b1.y)
                 + dot2(a1.z, b1.z) + dot2(a1.w, b1.w);
        }
        float4 rh = ((const float4*)rhn)[h];
        float lx, ly, lz, lw;
        if (first) { lx = ly = lz = lw = -LOG4; }
        else {
            float4 p0 = ((const float4*)P)[j];
            lx = __logf(p0.x); ly = __logf(p0.y);
            lz = __logf(p0.z); lw = __logf(p0.w);
        }
        float y0 = lx + rh.x * d[0], y1 = ly + rh.y * d[1],
              y2 = lz + rh.z * d[2], y3 = lw + rh.w * d[3];
        float m = fmaxf(fmaxf(y0, y1), fmaxf(y2, y3));
        float e0 = __expf(y0 - m), e1 = __expf(y1 - m),
              e2 = __expf(y2 - m), e3 = __expf(y3 - m);
        float inv = 1.0f / (e0 + e1 + e2 + e3);
        float p0n = e0 * inv, p1n = e1 * inv, p2n = e2 * inv, p3n = e3 * inv;
        ((float4*)P)[j] = make_float4(p0n, p1n, p2n, p3n);
        s_p[tid][0] = p0n; s_p[tid][1] = p1n; s_p[tid][2] = p2n; s_p[tid][3] = p3n;
    }
    s_h[tid] = h;
    __syncthreads();
    if (h == -1) return;
    if (tid > 0 && s_h[tid - 1] == h) return;   // not a segment head
    float a0 = 0.f, a1 = 0.f, a2 = 0.f, a3 = 0.f;
    int k = tid;
    while (k < 256 && s_h[k] == h) {
        a0 += s_p[k][0]; a1 += s_p[k][1]; a2 += s_p[k][2]; a3 += s_p[k][3];
        ++k;
    }
    float* dst = dval + (size_t)h * 4;
    if (tid == 0 || k == 256) {   // may continue in adjacent block -> atomic
        unsafeAtomicAdd(dst + 0, a0);
        unsafeAtomicAdd(dst + 1, a1);
        unsafeAtomicAdd(dst + 2, a2);
        unsafeAtomicAdd(dst + 3, a3);
    } else {                      // fully interior segment -> plain store
        ((float4*)dst)[0] = make_float4(a0, a1, a2, a3);
    }
}

extern "C" void kernel_launch(void* const* d_in, const int* in_sizes, int n_in,
                              void* d_out, int out_size, void* d_ws, size_t ws_size,
                              hipStream_t stream) {
    const void* ue = d_in[0];
    const void* ie = d_in[1];
    const int* hl = (const int*)d_in[2];
    const int* tl = (const int*)d_in[3];
    float* out = (float*)d_out;

    float* ws    = (float*)d_ws;
    float* P     = ws;
    int*   bt    = (int*)(ws);              // overlaps P (dead before P first written)
    int*   cnt   = (int*)(ws + 1000000);    // overlaps P
    int*   gbase = (int*)(ws + 1262144);    // overlaps P
    float* dvA   = ws + 4000000;
    float* dvB   = ws + 4320000;
    float* rhn   = ws + 4640000;
    unsigned short* bufW = (unsigned short*)(ws + 4960000);   // input ego (bf16)
    unsigned short* bufX = (unsigned short*)(ws + 7520000);   // f0 / f2
    unsigned short* bufY = (unsigned short*)(ws + 10080000);  // f1 (layer-1 input)
    unsigned short* bufZ0 = (unsigned short*)(ws + 12640000); // layer-0 tnh
    unsigned short* bufZ1 = (unsigned short*)(ws + 15200000); // layer-1 tnh
    int*   flag = (int*)(ws + 20320000);
    int*   boff = (int*)(ws + 20320016);    // 513 ints (bucket bases)
    int*   off  = (int*)(ws + 20400016);
    int*   tlist = (int*)(ws + 20480017);
    int*   hlist = (int*)(ws + 21480017);

    k_detect<<<1, 256, 0, stream>>>((const unsigned short*)ue, flag);
    k_init<<<20000, 256, 0, stream>>>(ue, ie, flag, bufW, bufZ0);

    // CSR build: no global atomics anywhere
    k_bcnt<<<BBLK, 256, 0, stream>>>(hl, cnt);
    k_btot<<<1, NBUCK, 0, stream>>>(cnt, boff);
    k_bscan<<<NBUCK, BBLK, 0, stream>>>(cnt, boff, gbase);
    k_bscat<<<BBLK, 256, 0, stream>>>(hl, tl, gbase, bt);
    k_bfin<<<NBUCK, 256, 0, stream>>>(bt, boff, off, dvA, tlist, hlist);

    // layer 0 (ego = bufW)
    k_mp<<<20000, 256, 0, stream>>>(bufW, P, dvA, dvB, off, tlist, bufX, rhn, bufZ1,
                                    bufY, ue, ie, flag, out, 0, 1, 0, 0);
    k_upd<<<3907, 256, 0, stream>>>(bufX, bufZ0, rhn, hlist, tlist, P, dvB, 1);
    k_mp<<<20000, 256, 0, stream>>>(bufW, P, dvB, dvA, off, tlist, bufY, rhn, bufZ1,
                                    bufY, ue, ie, flag, out, 1, 1, 1, 0);
    k_upd<<<3907, 256, 0, stream>>>(bufY, bufZ0, rhn, hlist, tlist, P, dvA, 0);
    // layer 1 (ego = bufY)
    k_mp<<<20000, 256, 0, stream>>>(bufY, P, dvA, dvB, off, tlist, bufX, rhn, bufZ1,
                                    bufY, ue, ie, flag, out, 1, 1, 0, 0);
    k_upd<<<3907, 256, 0, stream>>>(bufX, bufZ1, rhn, hlist, tlist, P, dvB, 0);
    k_mp<<<20000, 256, 0, stream>>>(bufY, P, dvB, nullptr, off, tlist, bufX, rhn, bufZ1,
                                    bufY, ue, ie, flag, out, 1, 0, 0, 1);
}